// Round 1
// baseline (1121.076 us; speedup 1.0000x reference)
//
#include <hip/hip_runtime.h>

// BoWExtractor: x(128,197,768) f32, emb(4096,768) f32 (pre-L2-normalized).
//   xn = l2norm(x[:,1:,:]); logits = 30 * xn @ emb^T   (M=25088, N=4096, K=768)
//   codes = softmax(logits, axis=-1)                    -> d_out[524288:]
//   bow   = mean(codes[:, keep100, :], axis=1), L1-norm -> d_out[0:524288]
//
// Precision: bf16 hi/lo split, 3 MFMA passes (hh + hl + lh) => ~fp32-accurate
// dot products. |logit| <= 30 so exp() needs no max-subtraction.
//
// R2: (a) XOR-swizzled LDS chunk layout kills 8-way ds_read_b128 bank
//     conflicts; (b) rescale pass: float4 RMW + LDS-cached reciprocal rowsums.
// R3: (a) rescale was latency-bound (512 blocks = 2/CU, unroll 2 => ~16KB
//     in flight per CU vs ~25-30KB needed): split rows into 4 groups
//     (grid 2048, up to 8 blocks/CU) + hand-batched 7-deep load groups;
//     bow partials via atomicAdd, L1 moved into bow_norm (block/image).
//     (b) gemm __launch_bounds__(256,4): LDS allows 4 blocks/CU; occupancy
//     was 33% — let neighbor blocks' MFMA cover the barrier vmcnt drain.

typedef unsigned short ushort_t;
typedef short short8 __attribute__((ext_vector_type(8)));
typedef float float4_ __attribute__((ext_vector_type(4)));

#define M_ROWS 25088   // 128*196
#define N_COLS 4096
#define K_DIM  768
#define BM 128
#define BN 128
#define BK 32

__device__ __forceinline__ unsigned short f2bf_rne(float f) {
  unsigned u = __float_as_uint(f);
  unsigned r = u + 0x7fffu + ((u >> 16) & 1u);
  return (unsigned short)(r >> 16);
}
__device__ __forceinline__ float bf2f(unsigned short h) {
  return __uint_as_float(((unsigned)h) << 16);
}

__device__ __forceinline__ void gload16(const void* g, void* l) {
  __builtin_amdgcn_global_load_lds(
      (__attribute__((address_space(1))) void*)g,
      (__attribute__((address_space(3))) void*)l, 16, 0, 0);
}

// ---------------- kernel 1a: split embedding into bf16 hi/lo ----------------
__global__ void split_emb_kernel(const float* __restrict__ emb,
                                 ushort_t* __restrict__ Bh,
                                 ushort_t* __restrict__ Bl) {
  int t = blockIdx.x * 256 + threadIdx.x;   // < 4096*768 = 3145728
  float f = emb[t];
  unsigned short h = f2bf_rne(f);
  Bh[t] = h;
  Bl[t] = f2bf_rne(f - bf2f(h));
}

// ------------- kernel 1b: l2-normalize x rows (skip token 0), split ---------
__global__ void norm_split_x_kernel(const float* __restrict__ x,
                                    ushort_t* __restrict__ Ah,
                                    ushort_t* __restrict__ Al) {
  int m = blockIdx.x;                 // row 0..25087
  int n = m / 196;
  int l = m - n * 196;
  size_t src = ((size_t)n * 197 + 1 + l) * 768;
  int t = threadIdx.x;

  float v0 = x[src + t];
  float v1 = x[src + t + 256];
  float v2 = x[src + t + 512];
  float s = v0 * v0 + v1 * v1 + v2 * v2;
  #pragma unroll
  for (int off = 32; off; off >>= 1) s += __shfl_xor(s, off, 64);
  __shared__ float ws4[4];
  if ((t & 63) == 0) ws4[t >> 6] = s;
  __syncthreads();
  s = ws4[0] + ws4[1] + ws4[2] + ws4[3];
  float scale = 1.0f / fmaxf(sqrtf(s), 1e-5f);

  size_t dst = (size_t)m * 768;
  float f[3] = {v0 * scale, v1 * scale, v2 * scale};
  int idx[3] = {t, t + 256, t + 512};
  #pragma unroll
  for (int i = 0; i < 3; i++) {
    unsigned short h = f2bf_rne(f[i]);
    Ah[dst + idx[i]] = h;
    Al[dst + idx[i]] = f2bf_rne(f[i] - bf2f(h));
  }
}

// ---------------- kernel 2: GEMM (3-pass bf16) + exp + row sums -------------
// LDS layout is XOR-swizzled: 16B chunk c of row R lives at slot c ^ ((R>>1)&3).
// Staging permutes which GLOBAL chunk each lane fetches (same 64B line, so
// coalescing is unchanged and the wave-uniform-base rule of global_load_lds
// holds); fragment ds_read_b128 then see only 2-way bank aliasing (free).
__global__ __launch_bounds__(256, 4)
void gemm_exp_kernel(const ushort_t* __restrict__ Ah, const ushort_t* __restrict__ Al,
                     const ushort_t* __restrict__ Bh, const ushort_t* __restrict__ Bl,
                     float* __restrict__ codes, float* __restrict__ rowsum) {
  __shared__ __attribute__((aligned(16))) ushort_t sAh[BM * BK];
  __shared__ __attribute__((aligned(16))) ushort_t sAl[BM * BK];
  __shared__ __attribute__((aligned(16))) ushort_t sBh[BM * BK];
  __shared__ __attribute__((aligned(16))) ushort_t sBl[BM * BK];
  __shared__ float rs[BM];

  const int t = threadIdx.x;
  const int w = t >> 6;
  const int lane = t & 63;
  const int row0 = blockIdx.x * BM;   // M tile base (196 blocks)
  const int col0 = blockIdx.y * BN;   // N tile base (32 blocks)

  if (t < BM) rs[t] = 0.f;

  float4_ acc[4][4];
  #pragma unroll
  for (int i = 0; i < 4; i++)
    #pragma unroll
    for (int j = 0; j < 4; j++) acc[i][j] = (float4_){0.f, 0.f, 0.f, 0.f};

  // staging: LDS slot u = t (+256 for 2nd half); row r0 = t>>2.
  // global chunk fetched = (t&3) ^ ((r0>>1)&3)  [swizzle; same for r0+64]
  const int r0 = t >> 2;
  const int c0 = (((t & 3) ^ ((r0 >> 1) & 3))) * 8;
  const ushort_t* gA = Ah + (size_t)(row0 + r0) * K_DIM + c0;
  const ushort_t* gAl_ = Al + (size_t)(row0 + r0) * K_DIM + c0;
  const ushort_t* gB = Bh + (size_t)(col0 + r0) * K_DIM + c0;
  const ushort_t* gBl_ = Bl + (size_t)(col0 + r0) * K_DIM + c0;
  const int half = 64 * K_DIM;        // second 64 rows of the tile
  const int ldsw = w * 512;           // wave-uniform LDS base (ushorts)

  const int rl = (w >> 1) * 64;       // wave row base in tile
  const int cl = (w & 1) * 64;        // wave col base in tile
  const int lq = lane >> 4;           // quad 0..3 (k-chunk)
  const int li = lane & 15;
  // swizzled fragment base: f(R) = (li>>1)&3 (row bases are mult. of 16)
  const int fsw = (li >> 1) & 3;
  const int abase = (rl + li) * BK + (lq ^ fsw) * 8;
  const int bbase = (cl + li) * BK + (lq ^ fsw) * 8;

  for (int kk = 0; kk < K_DIM; kk += BK) {
    __syncthreads();
    gload16(gA + kk,           sAh + ldsw);
    gload16(gA + kk + half,    sAh + 2048 + ldsw);
    gload16(gAl_ + kk,         sAl + ldsw);
    gload16(gAl_ + kk + half,  sAl + 2048 + ldsw);
    gload16(gB + kk,           sBh + ldsw);
    gload16(gB + kk + half,    sBh + 2048 + ldsw);
    gload16(gBl_ + kk,         sBl + ldsw);
    gload16(gBl_ + kk + half,  sBl + 2048 + ldsw);
    __syncthreads();

    short8 ah[4], al[4], bh[4], bl[4];
    #pragma unroll
    for (int i = 0; i < 4; i++) {
      ah[i] = *(const short8*)(sAh + abase + i * 16 * BK);
      al[i] = *(const short8*)(sAl + abase + i * 16 * BK);
      bh[i] = *(const short8*)(sBh + bbase + i * 16 * BK);
      bl[i] = *(const short8*)(sBl + bbase + i * 16 * BK);
    }
    #pragma unroll
    for (int i = 0; i < 4; i++)
      #pragma unroll
      for (int j = 0; j < 4; j++) {
        acc[i][j] = __builtin_amdgcn_mfma_f32_16x16x32_bf16(ah[i], bh[j], acc[i][j], 0, 0, 0);
        acc[i][j] = __builtin_amdgcn_mfma_f32_16x16x32_bf16(ah[i], bl[j], acc[i][j], 0, 0, 0);
        acc[i][j] = __builtin_amdgcn_mfma_f32_16x16x32_bf16(al[i], bh[j], acc[i][j], 0, 0, 0);
      }
  }

  // epilogue: e = exp(30*dot); store unnormalized; accumulate row sums
  float rsum[4][4];
  #pragma unroll
  for (int i = 0; i < 4; i++)
    #pragma unroll
    for (int r = 0; r < 4; r++) rsum[i][r] = 0.f;

  #pragma unroll
  for (int i = 0; i < 4; i++)
    #pragma unroll
    for (int j = 0; j < 4; j++)
      #pragma unroll
      for (int r = 0; r < 4; r++) {
        float e = __expf(30.0f * acc[i][j][r]);
        size_t row = (size_t)(row0 + rl + i * 16 + lq * 4 + r);
        size_t col = (size_t)(col0 + cl + j * 16 + li);
        codes[row * N_COLS + col] = e;
        rsum[i][r] += e;
      }

  #pragma unroll
  for (int i = 0; i < 4; i++)
    #pragma unroll
    for (int r = 0; r < 4; r++) {
      float v = rsum[i][r];
      v += __shfl_xor(v, 1, 64);
      v += __shfl_xor(v, 2, 64);
      v += __shfl_xor(v, 4, 64);
      v += __shfl_xor(v, 8, 64);
      if (li == 0) atomicAdd(&rs[rl + i * 16 + lq * 4 + r], v);
    }
  __syncthreads();
  if (t < BM) atomicAdd(&rowsum[row0 + t], rs[t]);
}

// ------------- kernel 3: rescale codes in place, accumulate bow -------------
// R3: grid = 128 images x 4 column chunks x 4 row groups = 2048 blocks
// (up to 8 blocks/CU vs 2 before). Each thread RMWs 49 float4s, loads
// batched 7-deep so 7 loads stay in flight (latency-bound fix).
// bow partials accumulated with atomicAdd into bow_un (memset to 0 first).
__global__ __launch_bounds__(256)
void rescale_bow_kernel(float* __restrict__ codes,
                        const float* __restrict__ rowsum,
                        float* __restrict__ bow_un) {
  const int bid = blockIdx.x;
  const int n = bid >> 4;            // image 0..127
  const int g = (bid >> 2) & 3;      // row group 0..3 (49 rows each)
  const int chunk = bid & 3;         // column chunk 0..3
  const int t = threadIdx.x;
  const int k4 = chunk * 256 + t;    // float4 index in row, 0..1023
  const int l0 = g * 49;

  __shared__ float inv[49];
  __shared__ float keep[49];
  if (t < 49) {
    int l = l0 + t;
    inv[t] = 1.0f / rowsum[n * 196 + l];
    int rr = l / 14;
    int cc = l - rr * 14;
    keep[t] = (rr >= 2 && rr <= 11 && cc >= 2 && cc <= 11) ? 0.01f : 0.0f;
  }
  __syncthreads();

  float4_* base = (float4_*)(codes + (size_t)n * 196 * N_COLS)
                  + (size_t)l0 * 1024 + k4;
  float4_ acc = {0.f, 0.f, 0.f, 0.f};
  #pragma unroll
  for (int c = 0; c < 7; c++) {
    float4_ v[7];
    #pragma unroll
    for (int u = 0; u < 7; u++) v[u] = base[(size_t)(c * 7 + u) * 1024];
    #pragma unroll
    for (int u = 0; u < 7; u++) {
      int l = c * 7 + u;
      float iv = inv[l];
      v[u].x *= iv; v[u].y *= iv; v[u].z *= iv; v[u].w *= iv;
      base[(size_t)l * 1024] = v[u];
      float kf = keep[l];
      acc.x += kf * v[u].x; acc.y += kf * v[u].y;
      acc.z += kf * v[u].z; acc.w += kf * v[u].w;
    }
  }

  float* dst = bow_un + (size_t)n * N_COLS + (size_t)k4 * 4;
  atomicAdd(dst + 0, acc.x);
  atomicAdd(dst + 1, acc.y);
  atomicAdd(dst + 2, acc.z);
  atomicAdd(dst + 3, acc.w);
}

// ---------------- kernel 4: finalize bow L1 normalization -------------------
// One block per image: read summed bow_un row, L1-reduce, normalize, write.
__global__ __launch_bounds__(256)
void bow_norm_kernel(const float* __restrict__ bow_un,
                     float* __restrict__ bow_out) {
  const int n = blockIdx.x;
  const int t = threadIdx.x;
  const float4_* src = (const float4_*)(bow_un + (size_t)n * N_COLS);
  float4_ v[4];
  float s = 0.f;
  #pragma unroll
  for (int i = 0; i < 4; i++) {
    v[i] = src[t + i * 256];
    s += fabsf(v[i].x) + fabsf(v[i].y) + fabsf(v[i].z) + fabsf(v[i].w);
  }
  #pragma unroll
  for (int off = 32; off; off >>= 1) s += __shfl_xor(s, off, 64);
  __shared__ float ws4[4];
  if ((t & 63) == 0) ws4[t >> 6] = s;
  __syncthreads();
  float invn = 1.0f / fmaxf(ws4[0] + ws4[1] + ws4[2] + ws4[3], 1e-5f);
  float4_* dst = (float4_*)(bow_out + (size_t)n * N_COLS);
  #pragma unroll
  for (int i = 0; i < 4; i++) {
    float4_ o = v[i];
    o.x *= invn; o.y *= invn; o.z *= invn; o.w *= invn;
    dst[t + i * 256] = o;
  }
}

extern "C" void kernel_launch(void* const* d_in, const int* in_sizes, int n_in,
                              void* d_out, int out_size, void* d_ws, size_t ws_size,
                              hipStream_t stream) {
  const float* x = (const float*)d_in[0];     // 128*197*768
  const float* emb = (const float*)d_in[1];   // 4096*768
  float* bow_out = (float*)d_out;             // 524288
  float* codes = (float*)d_out + 524288;      // 25088*4096

  // workspace layout (total ~92 MB)
  char* ws = (char*)d_ws;
  ushort_t* Ah = (ushort_t*)(ws + 0);                  // 25088*768*2 = 38535168
  ushort_t* Al = (ushort_t*)(ws + 38535168);           // 38535168
  ushort_t* Bh = (ushort_t*)(ws + 77070336);           // 4096*768*2 = 6291456
  ushort_t* Bl = (ushort_t*)(ws + 83361792);           // 6291456
  float* rowsum = (float*)(ws + 89653248);             // 25088*4 = 100352
  float* bow_un = (float*)(ws + 89753600);             // 524288*4 = 2097152

  hipMemsetAsync(rowsum, 0, 25088 * 4, stream);
  hipMemsetAsync(bow_un, 0, 524288 * 4, stream);

  split_emb_kernel<<<12288, 256, 0, stream>>>(emb, Bh, Bl);
  norm_split_x_kernel<<<25088, 256, 0, stream>>>(x, Ah, Al);

  dim3 ggrid(M_ROWS / BM, N_COLS / BN);   // 196 x 32
  gemm_exp_kernel<<<ggrid, 256, 0, stream>>>(Ah, Al, Bh, Bl, codes, rowsum);

  rescale_bow_kernel<<<2048, 256, 0, stream>>>(codes, rowsum, bow_un);
  bow_norm_kernel<<<128, 256, 0, stream>>>(bow_un, bow_out);
}

// Round 2
// 1056.948 us; speedup vs baseline: 1.0607x; 1.0607x over previous
//
#include <hip/hip_runtime.h>

// BoWExtractor: x(128,197,768) f32, emb(4096,768) f32 (pre-L2-normalized).
//   xn = l2norm(x[:,1:,:]); logits = 30 * xn @ emb^T   (M=25088, N=4096, K=768)
//   codes = softmax(logits, axis=-1)                    -> d_out[524288:]
//   bow   = mean(codes[:, keep100, :], axis=1), L1-norm -> d_out[0:524288]
//
// Precision: bf16 hi/lo split, 3 MFMA passes (hh + hl + lh) => ~fp32-accurate
// dot products. |logit| <= 30 so exp() needs no max-subtraction.
//
// R2: XOR-swizzled LDS chunk layout kills ds_read_b128 bank conflicts.
// R3: rescale: 2048 blocks + 7-deep batched loads (measured neutral; keep).
//     gemm launch_bounds(256,4) REGRESSED (L2 thrash: FETCH +200MB) -> revert.
// R4: T3+T4 (learn_hip m218/m230/m248): double-buffered LDS K-loop with raw
//     s_barrier + counted s_waitcnt vmcnt(8) -- prefetch for K-step t+1 stays
//     in flight across the barriers while t computes. Never vmcnt(0) in the
//     main loop (the old __syncthreads drain was the documented ~20% stall
//     of this structure). Fragment math/swizzle/epilogue unchanged.

typedef unsigned short ushort_t;
typedef short short8 __attribute__((ext_vector_type(8)));
typedef float float4_ __attribute__((ext_vector_type(4)));

#define M_ROWS 25088   // 128*196
#define N_COLS 4096
#define K_DIM  768
#define BM 128
#define BN 128
#define BK 32
#define K_STEPS (K_DIM / BK)   // 24

__device__ __forceinline__ unsigned short f2bf_rne(float f) {
  unsigned u = __float_as_uint(f);
  unsigned r = u + 0x7fffu + ((u >> 16) & 1u);
  return (unsigned short)(r >> 16);
}
__device__ __forceinline__ float bf2f(unsigned short h) {
  return __uint_as_float(((unsigned)h) << 16);
}

__device__ __forceinline__ void gload16(const void* g, void* l) {
  __builtin_amdgcn_global_load_lds(
      (__attribute__((address_space(1))) void*)g,
      (__attribute__((address_space(3))) void*)l, 16, 0, 0);
}

// ---------------- kernel 1a: split embedding into bf16 hi/lo ----------------
__global__ void split_emb_kernel(const float* __restrict__ emb,
                                 ushort_t* __restrict__ Bh,
                                 ushort_t* __restrict__ Bl) {
  int t = blockIdx.x * 256 + threadIdx.x;   // < 4096*768 = 3145728
  float f = emb[t];
  unsigned short h = f2bf_rne(f);
  Bh[t] = h;
  Bl[t] = f2bf_rne(f - bf2f(h));
}

// ------------- kernel 1b: l2-normalize x rows (skip token 0), split ---------
__global__ void norm_split_x_kernel(const float* __restrict__ x,
                                    ushort_t* __restrict__ Ah,
                                    ushort_t* __restrict__ Al) {
  int m = blockIdx.x;                 // row 0..25087
  int n = m / 196;
  int l = m - n * 196;
  size_t src = ((size_t)n * 197 + 1 + l) * 768;
  int t = threadIdx.x;

  float v0 = x[src + t];
  float v1 = x[src + t + 256];
  float v2 = x[src + t + 512];
  float s = v0 * v0 + v1 * v1 + v2 * v2;
  #pragma unroll
  for (int off = 32; off; off >>= 1) s += __shfl_xor(s, off, 64);
  __shared__ float ws4[4];
  if ((t & 63) == 0) ws4[t >> 6] = s;
  __syncthreads();
  s = ws4[0] + ws4[1] + ws4[2] + ws4[3];
  float scale = 1.0f / fmaxf(sqrtf(s), 1e-5f);

  size_t dst = (size_t)m * 768;
  float f[3] = {v0 * scale, v1 * scale, v2 * scale};
  int idx[3] = {t, t + 256, t + 512};
  #pragma unroll
  for (int i = 0; i < 3; i++) {
    unsigned short h = f2bf_rne(f[i]);
    Ah[dst + idx[i]] = h;
    Al[dst + idx[i]] = f2bf_rne(f[i] - bf2f(h));
  }
}

// ---------------- kernel 2: GEMM (3-pass bf16) + exp + row sums -------------
// LDS layout is XOR-swizzled: 16B chunk c of row R lives at slot c ^ ((R>>1)&3).
// Staging permutes which GLOBAL chunk each lane fetches (same 64B line, so
// coalescing is unchanged and the wave-uniform-base rule of global_load_lds
// holds); fragment ds_read_b128 then see only 2-way bank aliasing (free).
//
// R4 loop structure (T3+T4): two LDS buffers; per K-step issue the 8
// global_load_lds for step t+1, then s_waitcnt vmcnt(8) (waits only for the
// 8 OLDER loads of step t; the new 8 stay in flight), raw s_barrier,
// ds_read+MFMA from buf[t&1], raw s_barrier. No vmcnt(0) until the tail.
__global__ __launch_bounds__(256, 2)
void gemm_exp_kernel(const ushort_t* __restrict__ Ah, const ushort_t* __restrict__ Al,
                     const ushort_t* __restrict__ Bh, const ushort_t* __restrict__ Bl,
                     float* __restrict__ codes, float* __restrict__ rowsum) {
  __shared__ __attribute__((aligned(16))) ushort_t sAh[2][BM * BK];
  __shared__ __attribute__((aligned(16))) ushort_t sAl[2][BM * BK];
  __shared__ __attribute__((aligned(16))) ushort_t sBh[2][BM * BK];
  __shared__ __attribute__((aligned(16))) ushort_t sBl[2][BM * BK];
  __shared__ float rs[BM];

  const int t = threadIdx.x;
  const int w = t >> 6;
  const int lane = t & 63;
  const int row0 = blockIdx.x * BM;   // M tile base (196 blocks)
  const int col0 = blockIdx.y * BN;   // N tile base (32 blocks)

  if (t < BM) rs[t] = 0.f;

  float4_ acc[4][4];
  #pragma unroll
  for (int i = 0; i < 4; i++)
    #pragma unroll
    for (int j = 0; j < 4; j++) acc[i][j] = (float4_){0.f, 0.f, 0.f, 0.f};

  // staging: LDS slot u = t (+256 for 2nd half); row r0 = t>>2.
  // global chunk fetched = (t&3) ^ ((r0>>1)&3)  [swizzle; same for r0+64]
  const int r0 = t >> 2;
  const int c0 = (((t & 3) ^ ((r0 >> 1) & 3))) * 8;
  const ushort_t* gA = Ah + (size_t)(row0 + r0) * K_DIM + c0;
  const ushort_t* gAl_ = Al + (size_t)(row0 + r0) * K_DIM + c0;
  const ushort_t* gB = Bh + (size_t)(col0 + r0) * K_DIM + c0;
  const ushort_t* gBl_ = Bl + (size_t)(col0 + r0) * K_DIM + c0;
  const int half = 64 * K_DIM;        // second 64 rows of the tile
  const int ldsw = w * 512;           // wave-uniform LDS base (ushorts)

  const int rl = (w >> 1) * 64;       // wave row base in tile
  const int cl = (w & 1) * 64;        // wave col base in tile
  const int lq = lane >> 4;           // quad 0..3 (k-chunk)
  const int li = lane & 15;
  // swizzled fragment base: f(R) = (li>>1)&3 (row bases are mult. of 16)
  const int fsw = (li >> 1) & 3;
  const int abase = (rl + li) * BK + (lq ^ fsw) * 8;
  const int bbase = (cl + li) * BK + (lq ^ fsw) * 8;

  // issue the 8 staging loads for K-offset kk into LDS buffer b
  auto issue = [&](int b, int kk) {
    gload16(gA + kk,           &sAh[b][ldsw]);
    gload16(gA + kk + half,    &sAh[b][2048 + ldsw]);
    gload16(gAl_ + kk,         &sAl[b][ldsw]);
    gload16(gAl_ + kk + half,  &sAl[b][2048 + ldsw]);
    gload16(gB + kk,           &sBh[b][ldsw]);
    gload16(gB + kk + half,    &sBh[b][2048 + ldsw]);
    gload16(gBl_ + kk,         &sBl[b][ldsw]);
    gload16(gBl_ + kk + half,  &sBl[b][2048 + ldsw]);
  };

  // ds_read fragments from buffer b (compile-time 0/1) and run the 48 MFMAs
  auto compute = [&](int b) {
    short8 ah[4], al[4], bh[4], bl[4];
    #pragma unroll
    for (int i = 0; i < 4; i++) {
      ah[i] = *(const short8*)(&sAh[b][abase + i * 16 * BK]);
      al[i] = *(const short8*)(&sAl[b][abase + i * 16 * BK]);
      bh[i] = *(const short8*)(&sBh[b][bbase + i * 16 * BK]);
      bl[i] = *(const short8*)(&sBl[b][bbase + i * 16 * BK]);
    }
    #pragma unroll
    for (int i = 0; i < 4; i++)
      #pragma unroll
      for (int j = 0; j < 4; j++) {
        acc[i][j] = __builtin_amdgcn_mfma_f32_16x16x32_bf16(ah[i], bh[j], acc[i][j], 0, 0, 0);
        acc[i][j] = __builtin_amdgcn_mfma_f32_16x16x32_bf16(ah[i], bl[j], acc[i][j], 0, 0, 0);
        acc[i][j] = __builtin_amdgcn_mfma_f32_16x16x32_bf16(al[i], bh[j], acc[i][j], 0, 0, 0);
      }
  };

  // prologue: stage K-step 0 into buf 0
  issue(0, 0);

  // main loop: unrolled by 2 so LDS buffer indices are compile-time constant.
  // iterations t and t+1; prefetch always valid for t+1 <= K_STEPS-2.
  #pragma unroll 1
  for (int ks = 0; ks < K_STEPS - 2; ks += 2) {
    issue(1, (ks + 1) * BK);
    asm volatile("s_waitcnt vmcnt(8)" ::: "memory");
    __builtin_amdgcn_s_barrier();
    asm volatile("" ::: "memory");
    compute(0);
    asm volatile("" ::: "memory");
    __builtin_amdgcn_s_barrier();

    issue(0, (ks + 2) * BK);
    asm volatile("s_waitcnt vmcnt(8)" ::: "memory");
    __builtin_amdgcn_s_barrier();
    asm volatile("" ::: "memory");
    compute(1);
    asm volatile("" ::: "memory");
    __builtin_amdgcn_s_barrier();
  }

  // tail: K-step 22 (prefetch 23), then K-step 23 (full drain)
  issue(1, (K_STEPS - 1) * BK);
  asm volatile("s_waitcnt vmcnt(8)" ::: "memory");
  __builtin_amdgcn_s_barrier();
  asm volatile("" ::: "memory");
  compute(0);
  asm volatile("" ::: "memory");
  __builtin_amdgcn_s_barrier();

  asm volatile("s_waitcnt vmcnt(0)" ::: "memory");
  __builtin_amdgcn_s_barrier();
  asm volatile("" ::: "memory");
  compute(1);

  // epilogue: e = exp(30*dot); store unnormalized; accumulate row sums
  float rsum[4][4];
  #pragma unroll
  for (int i = 0; i < 4; i++)
    #pragma unroll
    for (int r = 0; r < 4; r++) rsum[i][r] = 0.f;

  #pragma unroll
  for (int i = 0; i < 4; i++)
    #pragma unroll
    for (int j = 0; j < 4; j++)
      #pragma unroll
      for (int r = 0; r < 4; r++) {
        float e = __expf(30.0f * acc[i][j][r]);
        size_t row = (size_t)(row0 + rl + i * 16 + lq * 4 + r);
        size_t col = (size_t)(col0 + cl + j * 16 + li);
        codes[row * N_COLS + col] = e;
        rsum[i][r] += e;
      }

  #pragma unroll
  for (int i = 0; i < 4; i++)
    #pragma unroll
    for (int r = 0; r < 4; r++) {
      float v = rsum[i][r];
      v += __shfl_xor(v, 1, 64);
      v += __shfl_xor(v, 2, 64);
      v += __shfl_xor(v, 4, 64);
      v += __shfl_xor(v, 8, 64);
      if (li == 0) atomicAdd(&rs[rl + i * 16 + lq * 4 + r], v);
    }
  __syncthreads();
  if (t < BM) atomicAdd(&rowsum[row0 + t], rs[t]);
}

// ------------- kernel 3: rescale codes in place, accumulate bow -------------
// grid = 128 images x 4 column chunks x 4 row groups = 2048 blocks
// (8 blocks/CU). Each thread RMWs 49 float4s, loads batched 7-deep.
// bow partials accumulated with atomicAdd into bow_un (memset to 0 first).
__global__ __launch_bounds__(256)
void rescale_bow_kernel(float* __restrict__ codes,
                        const float* __restrict__ rowsum,
                        float* __restrict__ bow_un) {
  const int bid = blockIdx.x;
  const int n = bid >> 4;            // image 0..127
  const int g = (bid >> 2) & 3;      // row group 0..3 (49 rows each)
  const int chunk = bid & 3;         // column chunk 0..3
  const int t = threadIdx.x;
  const int k4 = chunk * 256 + t;    // float4 index in row, 0..1023
  const int l0 = g * 49;

  __shared__ float inv[49];
  __shared__ float keep[49];
  if (t < 49) {
    int l = l0 + t;
    inv[t] = 1.0f / rowsum[n * 196 + l];
    int rr = l / 14;
    int cc = l - rr * 14;
    keep[t] = (rr >= 2 && rr <= 11 && cc >= 2 && cc <= 11) ? 0.01f : 0.0f;
  }
  __syncthreads();

  float4_* base = (float4_*)(codes + (size_t)n * 196 * N_COLS)
                  + (size_t)l0 * 1024 + k4;
  float4_ acc = {0.f, 0.f, 0.f, 0.f};
  #pragma unroll
  for (int c = 0; c < 7; c++) {
    float4_ v[7];
    #pragma unroll
    for (int u = 0; u < 7; u++) v[u] = base[(size_t)(c * 7 + u) * 1024];
    #pragma unroll
    for (int u = 0; u < 7; u++) {
      int l = c * 7 + u;
      float iv = inv[l];
      v[u].x *= iv; v[u].y *= iv; v[u].z *= iv; v[u].w *= iv;
      base[(size_t)l * 1024] = v[u];
      float kf = keep[l];
      acc.x += kf * v[u].x; acc.y += kf * v[u].y;
      acc.z += kf * v[u].z; acc.w += kf * v[u].w;
    }
  }

  float* dst = bow_un + (size_t)n * N_COLS + (size_t)k4 * 4;
  atomicAdd(dst + 0, acc.x);
  atomicAdd(dst + 1, acc.y);
  atomicAdd(dst + 2, acc.z);
  atomicAdd(dst + 3, acc.w);
}

// ---------------- kernel 4: finalize bow L1 normalization -------------------
// One block per image: read summed bow_un row, L1-reduce, normalize, write.
__global__ __launch_bounds__(256)
void bow_norm_kernel(const float* __restrict__ bow_un,
                     float* __restrict__ bow_out) {
  const int n = blockIdx.x;
  const int t = threadIdx.x;
  const float4_* src = (const float4_*)(bow_un + (size_t)n * N_COLS);
  float4_ v[4];
  float s = 0.f;
  #pragma unroll
  for (int i = 0; i < 4; i++) {
    v[i] = src[t + i * 256];
    s += fabsf(v[i].x) + fabsf(v[i].y) + fabsf(v[i].z) + fabsf(v[i].w);
  }
  #pragma unroll
  for (int off = 32; off; off >>= 1) s += __shfl_xor(s, off, 64);
  __shared__ float ws4[4];
  if ((t & 63) == 0) ws4[t >> 6] = s;
  __syncthreads();
  float invn = 1.0f / fmaxf(ws4[0] + ws4[1] + ws4[2] + ws4[3], 1e-5f);
  float4_* dst = (float4_*)(bow_out + (size_t)n * N_COLS);
  #pragma unroll
  for (int i = 0; i < 4; i++) {
    float4_ o = v[i];
    o.x *= invn; o.y *= invn; o.z *= invn; o.w *= invn;
    dst[t + i * 256] = o;
  }
}

extern "C" void kernel_launch(void* const* d_in, const int* in_sizes, int n_in,
                              void* d_out, int out_size, void* d_ws, size_t ws_size,
                              hipStream_t stream) {
  const float* x = (const float*)d_in[0];     // 128*197*768
  const float* emb = (const float*)d_in[1];   // 4096*768
  float* bow_out = (float*)d_out;             // 524288
  float* codes = (float*)d_out + 524288;      // 25088*4096

  // workspace layout (total ~92 MB)
  char* ws = (char*)d_ws;
  ushort_t* Ah = (ushort_t*)(ws + 0);                  // 25088*768*2 = 38535168
  ushort_t* Al = (ushort_t*)(ws + 38535168);           // 38535168
  ushort_t* Bh = (ushort_t*)(ws + 77070336);           // 4096*768*2 = 6291456
  ushort_t* Bl = (ushort_t*)(ws + 83361792);           // 6291456
  float* rowsum = (float*)(ws + 89653248);             // 25088*4 = 100352
  float* bow_un = (float*)(ws + 89753600);             // 524288*4 = 2097152

  hipMemsetAsync(rowsum, 0, 25088 * 4, stream);
  hipMemsetAsync(bow_un, 0, 524288 * 4, stream);

  split_emb_kernel<<<12288, 256, 0, stream>>>(emb, Bh, Bl);
  norm_split_x_kernel<<<25088, 256, 0, stream>>>(x, Ah, Al);

  dim3 ggrid(M_ROWS / BM, N_COLS / BN);   // 196 x 32
  gemm_exp_kernel<<<ggrid, 256, 0, stream>>>(Ah, Al, Bh, Bl, codes, rowsum);

  rescale_bow_kernel<<<2048, 256, 0, stream>>>(codes, rowsum, bow_un);
  bow_norm_kernel<<<128, 256, 0, stream>>>(bow_un, bow_out);
}

// Round 4
// 1018.182 us; speedup vs baseline: 1.1011x; 1.0381x over previous
//
#include <hip/hip_runtime.h>

// BoWExtractor: x(128,197,768) f32, emb(4096,768) f32 (pre-L2-normalized).
//   xn = l2norm(x[:,1:,:]); logits = 30 * xn @ emb^T   (M=25088, N=4096, K=768)
//   codes = softmax(logits, axis=-1)                    -> d_out[524288:]
//   bow   = mean(codes[:, keep100, :], axis=1), L1-norm -> d_out[0:524288]
//
// Precision: bf16 hi/lo split, 3 MFMA passes (hh + hl + lh) => ~fp32-accurate
// dot products. |logit| <= 30 so exp() needs no max-subtraction.
//
// R2: XOR-swizzled LDS chunk layout kills ds_read_b128 bank conflicts.
// R4: double-buffered LDS K-loop, raw s_barrier + counted vmcnt(8). Lands at
//     the documented ~880 TF ceiling of the 128^2 2-phase structure.
// R5: cooperative softmax-finish FAILED correctness (cross-XCD staleness:
//     plain loads after __threadfence are not enough; data itself must be
//     agent-scope sc1). Reverted.
// R6: consolidation. (a) grid swap kept: x = col-tile (fast) so the 32
//     col-blocks of a row-tile are concurrent -> A panel shared in L2/L3
//     (FETCH 1.27GB -> expect ~0.35GB). (b) rescale+bow re-fused (R0
//     structure, known-correct): single 822MB RMW pass accumulates bow and
//     its L1 partials; no extra bow read of codes.

typedef unsigned short ushort_t;
typedef short short8 __attribute__((ext_vector_type(8)));
typedef float float4_ __attribute__((ext_vector_type(4)));

#define M_ROWS 25088   // 128*196
#define N_COLS 4096
#define K_DIM  768
#define BM 128
#define BN 128
#define BK 32
#define K_STEPS (K_DIM / BK)   // 24

__device__ __forceinline__ unsigned short f2bf_rne(float f) {
  unsigned u = __float_as_uint(f);
  unsigned r = u + 0x7fffu + ((u >> 16) & 1u);
  return (unsigned short)(r >> 16);
}
__device__ __forceinline__ float bf2f(unsigned short h) {
  return __uint_as_float(((unsigned)h) << 16);
}

__device__ __forceinline__ void gload16(const void* g, void* l) {
  __builtin_amdgcn_global_load_lds(
      (__attribute__((address_space(1))) void*)g,
      (__attribute__((address_space(3))) void*)l, 16, 0, 0);
}

// ---------------- kernel 1a: split embedding into bf16 hi/lo ----------------
__global__ void split_emb_kernel(const float* __restrict__ emb,
                                 ushort_t* __restrict__ Bh,
                                 ushort_t* __restrict__ Bl) {
  int t = blockIdx.x * 256 + threadIdx.x;   // < 4096*768 = 3145728
  float f = emb[t];
  unsigned short h = f2bf_rne(f);
  Bh[t] = h;
  Bl[t] = f2bf_rne(f - bf2f(h));
}

// ------------- kernel 1b: l2-normalize x rows (skip token 0), split ---------
__global__ void norm_split_x_kernel(const float* __restrict__ x,
                                    ushort_t* __restrict__ Ah,
                                    ushort_t* __restrict__ Al) {
  int m = blockIdx.x;                 // row 0..25087
  int n = m / 196;
  int l = m - n * 196;
  size_t src = ((size_t)n * 197 + 1 + l) * 768;
  int t = threadIdx.x;

  float v0 = x[src + t];
  float v1 = x[src + t + 256];
  float v2 = x[src + t + 512];
  float s = v0 * v0 + v1 * v1 + v2 * v2;
  #pragma unroll
  for (int off = 32; off; off >>= 1) s += __shfl_xor(s, off, 64);
  __shared__ float ws4[4];
  if ((t & 63) == 0) ws4[t >> 6] = s;
  __syncthreads();
  s = ws4[0] + ws4[1] + ws4[2] + ws4[3];
  float scale = 1.0f / fmaxf(sqrtf(s), 1e-5f);

  size_t dst = (size_t)m * 768;
  float f[3] = {v0 * scale, v1 * scale, v2 * scale};
  int idx[3] = {t, t + 256, t + 512};
  #pragma unroll
  for (int i = 0; i < 3; i++) {
    unsigned short h = f2bf_rne(f[i]);
    Ah[dst + idx[i]] = h;
    Al[dst + idx[i]] = f2bf_rne(f[i] - bf2f(h));
  }
}

// ---------------- kernel 2: GEMM (3-pass bf16) + exp + row sums -------------
// LDS layout is XOR-swizzled: 16B chunk c of row R lives at slot c ^ ((R>>1)&3).
// K-loop: two LDS buffers; issue 8 global_load_lds for step t+1, then
// s_waitcnt vmcnt(8) (waits only for step t's 8 older loads), raw s_barrier,
// ds_read+MFMA from buf[t&1], raw s_barrier. vmcnt(0) only in the tail.
__global__ __launch_bounds__(256, 2)
void gemm_exp_kernel(const ushort_t* __restrict__ Ah, const ushort_t* __restrict__ Al,
                     const ushort_t* __restrict__ Bh, const ushort_t* __restrict__ Bl,
                     float* __restrict__ codes, float* __restrict__ rowsum) {
  __shared__ __attribute__((aligned(16))) ushort_t sAh[2][BM * BK];
  __shared__ __attribute__((aligned(16))) ushort_t sAl[2][BM * BK];
  __shared__ __attribute__((aligned(16))) ushort_t sBh[2][BM * BK];
  __shared__ __attribute__((aligned(16))) ushort_t sBl[2][BM * BK];
  __shared__ float rs[BM];

  const int t = threadIdx.x;
  const int w = t >> 6;
  const int lane = t & 63;
  const int row0 = blockIdx.y * BM;   // M tile base (196 tiles, y = slow dim)
  const int col0 = blockIdx.x * BN;   // N tile base (32 tiles, x = fast dim)

  if (t < BM) rs[t] = 0.f;

  float4_ acc[4][4];
  #pragma unroll
  for (int i = 0; i < 4; i++)
    #pragma unroll
    for (int j = 0; j < 4; j++) acc[i][j] = (float4_){0.f, 0.f, 0.f, 0.f};

  // staging: LDS slot u = t (+256 for 2nd half); row r0 = t>>2.
  // global chunk fetched = (t&3) ^ ((r0>>1)&3)  [swizzle; same for r0+64]
  const int r0 = t >> 2;
  const int c0 = (((t & 3) ^ ((r0 >> 1) & 3))) * 8;
  const ushort_t* gA = Ah + (size_t)(row0 + r0) * K_DIM + c0;
  const ushort_t* gAl_ = Al + (size_t)(row0 + r0) * K_DIM + c0;
  const ushort_t* gB = Bh + (size_t)(col0 + r0) * K_DIM + c0;
  const ushort_t* gBl_ = Bl + (size_t)(col0 + r0) * K_DIM + c0;
  const int half = 64 * K_DIM;        // second 64 rows of the tile
  const int ldsw = w * 512;           // wave-uniform LDS base (ushorts)

  const int rl = (w >> 1) * 64;       // wave row base in tile
  const int cl = (w & 1) * 64;        // wave col base in tile
  const int lq = lane >> 4;           // quad 0..3 (k-chunk)
  const int li = lane & 15;
  // swizzled fragment base: f(R) = (li>>1)&3 (row bases are mult. of 16)
  const int fsw = (li >> 1) & 3;
  const int abase = (rl + li) * BK + (lq ^ fsw) * 8;
  const int bbase = (cl + li) * BK + (lq ^ fsw) * 8;

  auto issue = [&](int b, int kk) {
    gload16(gA + kk,           &sAh[b][ldsw]);
    gload16(gA + kk + half,    &sAh[b][2048 + ldsw]);
    gload16(gAl_ + kk,         &sAl[b][ldsw]);
    gload16(gAl_ + kk + half,  &sAl[b][2048 + ldsw]);
    gload16(gB + kk,           &sBh[b][ldsw]);
    gload16(gB + kk + half,    &sBh[b][2048 + ldsw]);
    gload16(gBl_ + kk,         &sBl[b][ldsw]);
    gload16(gBl_ + kk + half,  &sBl[b][2048 + ldsw]);
  };

  auto compute = [&](int b) {
    short8 ah[4], al[4], bh[4], bl[4];
    #pragma unroll
    for (int i = 0; i < 4; i++) {
      ah[i] = *(const short8*)(&sAh[b][abase + i * 16 * BK]);
      al[i] = *(const short8*)(&sAl[b][abase + i * 16 * BK]);
      bh[i] = *(const short8*)(&sBh[b][bbase + i * 16 * BK]);
      bl[i] = *(const short8*)(&sBl[b][bbase + i * 16 * BK]);
    }
    #pragma unroll
    for (int i = 0; i < 4; i++)
      #pragma unroll
      for (int j = 0; j < 4; j++) {
        acc[i][j] = __builtin_amdgcn_mfma_f32_16x16x32_bf16(ah[i], bh[j], acc[i][j], 0, 0, 0);
        acc[i][j] = __builtin_amdgcn_mfma_f32_16x16x32_bf16(ah[i], bl[j], acc[i][j], 0, 0, 0);
        acc[i][j] = __builtin_amdgcn_mfma_f32_16x16x32_bf16(al[i], bh[j], acc[i][j], 0, 0, 0);
      }
  };

  issue(0, 0);

  #pragma unroll 1
  for (int ks = 0; ks < K_STEPS - 2; ks += 2) {
    issue(1, (ks + 1) * BK);
    asm volatile("s_waitcnt vmcnt(8)" ::: "memory");
    __builtin_amdgcn_s_barrier();
    asm volatile("" ::: "memory");
    compute(0);
    asm volatile("" ::: "memory");
    __builtin_amdgcn_s_barrier();

    issue(0, (ks + 2) * BK);
    asm volatile("s_waitcnt vmcnt(8)" ::: "memory");
    __builtin_amdgcn_s_barrier();
    asm volatile("" ::: "memory");
    compute(1);
    asm volatile("" ::: "memory");
    __builtin_amdgcn_s_barrier();
  }

  issue(1, (K_STEPS - 1) * BK);
  asm volatile("s_waitcnt vmcnt(8)" ::: "memory");
  __builtin_amdgcn_s_barrier();
  asm volatile("" ::: "memory");
  compute(0);
  asm volatile("" ::: "memory");
  __builtin_amdgcn_s_barrier();

  asm volatile("s_waitcnt vmcnt(0)" ::: "memory");
  __builtin_amdgcn_s_barrier();
  asm volatile("" ::: "memory");
  compute(1);

  // epilogue: e = exp(30*dot); store unnormalized; accumulate row sums
  float rsum[4][4];
  #pragma unroll
  for (int i = 0; i < 4; i++)
    #pragma unroll
    for (int r = 0; r < 4; r++) rsum[i][r] = 0.f;

  #pragma unroll
  for (int i = 0; i < 4; i++)
    #pragma unroll
    for (int j = 0; j < 4; j++)
      #pragma unroll
      for (int r = 0; r < 4; r++) {
        float e = __expf(30.0f * acc[i][j][r]);
        size_t row = (size_t)(row0 + rl + i * 16 + lq * 4 + r);
        size_t col = (size_t)(col0 + cl + j * 16 + li);
        codes[row * N_COLS + col] = e;
        rsum[i][r] += e;
      }

  #pragma unroll
  for (int i = 0; i < 4; i++)
    #pragma unroll
    for (int r = 0; r < 4; r++) {
      float v = rsum[i][r];
      v += __shfl_xor(v, 1, 64);
      v += __shfl_xor(v, 2, 64);
      v += __shfl_xor(v, 4, 64);
      v += __shfl_xor(v, 8, 64);
      if (li == 0) atomicAdd(&rs[rl + i * 16 + lq * 4 + r], v);
    }
  __syncthreads();
  if (t < BM) atomicAdd(&rowsum[row0 + t], rs[t]);
}

// ------------- kernel 3: rescale codes in place, accumulate bow -------------
// grid: 128 images x 4 column chunks (1024 floats each); block 256 threads,
// one float4 per thread, all 196 rows, 14-deep load batches for MLP latency.
// bow partials written directly (block owns its 1024 outputs); L1 partial
// via one atomicAdd per block.
__global__ __launch_bounds__(256)
void rescale_bow_kernel(float* __restrict__ codes,
                        const float* __restrict__ rowsum,
                        float* __restrict__ bow_un,
                        float* __restrict__ bow_l1) {
  const int n = blockIdx.x >> 2;
  const int t = threadIdx.x;
  const int k4 = (blockIdx.x & 3) * 256 + t;   // float4 index in row, 0..1023

  __shared__ float inv[196];
  __shared__ float keep[196];
  if (t < 196) {
    inv[t] = 1.0f / rowsum[n * 196 + t];
    int rr = t / 14;
    int cc = t - rr * 14;
    keep[t] = (rr >= 2 && rr <= 11 && cc >= 2 && cc <= 11) ? 0.01f : 0.0f;
  }
  __syncthreads();

  float4_* base = (float4_*)(codes + (size_t)n * 196 * N_COLS) + k4;
  float4_ acc = {0.f, 0.f, 0.f, 0.f};
  #pragma unroll 1
  for (int c = 0; c < 14; c++) {
    float4_ v[14];
    #pragma unroll
    for (int u = 0; u < 14; u++) v[u] = base[(size_t)(c * 14 + u) * 1024];
    #pragma unroll
    for (int u = 0; u < 14; u++) {
      int l = c * 14 + u;
      float iv = inv[l];
      v[u].x *= iv; v[u].y *= iv; v[u].z *= iv; v[u].w *= iv;
      base[(size_t)l * 1024] = v[u];
      float kf = keep[l];
      acc.x += kf * v[u].x; acc.y += kf * v[u].y;
      acc.z += kf * v[u].z; acc.w += kf * v[u].w;
    }
  }

  ((float4_*)(bow_un + (size_t)n * N_COLS))[k4] = acc;

  float s = fabsf(acc.x) + fabsf(acc.y) + fabsf(acc.z) + fabsf(acc.w);
  #pragma unroll
  for (int off = 32; off; off >>= 1) s += __shfl_xor(s, off, 64);
  __shared__ float wsum[4];
  if ((t & 63) == 0) wsum[t >> 6] = s;
  __syncthreads();
  if (t == 0) atomicAdd(&bow_l1[n], wsum[0] + wsum[1] + wsum[2] + wsum[3]);
}

// ---------------- kernel 4: finalize bow L1 normalization -------------------
__global__ void bow_norm_kernel(const float* __restrict__ bow_un,
                                const float* __restrict__ bow_l1,
                                float* __restrict__ bow_out) {
  int t = blockIdx.x * 256 + threadIdx.x;   // < 128*4096
  int n = t >> 12;
  bow_out[t] = bow_un[t] / fmaxf(bow_l1[n], 1e-5f);
}

extern "C" void kernel_launch(void* const* d_in, const int* in_sizes, int n_in,
                              void* d_out, int out_size, void* d_ws, size_t ws_size,
                              hipStream_t stream) {
  const float* x = (const float*)d_in[0];     // 128*197*768
  const float* emb = (const float*)d_in[1];   // 4096*768
  float* bow_out = (float*)d_out;             // 524288
  float* codes = (float*)d_out + 524288;      // 25088*4096

  // workspace layout (total ~92 MB)
  char* ws = (char*)d_ws;
  ushort_t* Ah = (ushort_t*)(ws + 0);                  // 25088*768*2 = 38535168
  ushort_t* Al = (ushort_t*)(ws + 38535168);           // 38535168
  ushort_t* Bh = (ushort_t*)(ws + 77070336);           // 4096*768*2 = 6291456
  ushort_t* Bl = (ushort_t*)(ws + 83361792);           // 6291456
  float* rowsum = (float*)(ws + 89653248);             // 25088*4 = 100352
  float* bow_un = (float*)(ws + 89753600);             // 524288*4 = 2097152
  float* bow_l1 = (float*)(ws + 91850752);             // 128*4

  hipMemsetAsync(rowsum, 0, 25088 * 4, stream);
  hipMemsetAsync(bow_l1, 0, 128 * 4, stream);

  split_emb_kernel<<<12288, 256, 0, stream>>>(emb, Bh, Bl);
  norm_split_x_kernel<<<25088, 256, 0, stream>>>(x, Ah, Al);

  dim3 ggrid(N_COLS / BN, M_ROWS / BM);   // (32 cols fast, 196 rows slow)
  gemm_exp_kernel<<<ggrid, 256, 0, stream>>>(Ah, Al, Bh, Bl, codes, rowsum);

  rescale_bow_kernel<<<512, 256, 0, stream>>>(codes, rowsum, bow_un, bow_l1);
  bow_norm_kernel<<<2048, 256, 0, stream>>>(bow_un, bow_l1, bow_out);
}